// Round 3
// baseline (112.057 us; speedup 1.0000x reference)
//
#include <hip/hip_runtime.h>

#define NSEQ   2048
#define HEADS  16
#define DIM    64
#define BATCH  2
#define SCALE  0.125f      // 1/sqrt(64)

// Workspace layout:
//   KVw : bf16 combined rows [b][slot][h][granule t]  where granule t (16 B)
//         = {k[4t..4t+3], v[4t..4t+3]} both bf16x4.  16.78 MB total.
//         One dwordx4 per (slot,h,t) fetches BOTH K and V fragments.
//   Kw6/Vw6 : fp32 lvl6 stash [b][32][h][d], 262 KB each (tree_top builds
//         from fp32 so bf16 rounding never compounds).
// Slot map: lvl1 0..1023, lvl2 1024.., lvl3 1536.., lvl4 1792.., lvl5 1920..,
// lvl6 1984.., lvl7 2016.., lvl8 2032.., lvl9 2040.., lvl10 2044,2045.
// Slots 2046,2047 are UNUSED -> slot 2046 is the dummy target for masked
// columns (R13).
// Invariant: parent(level_offset(j)+i) = level_offset(j+1)+i/2.
// NOTE (R8 lesson): do NOT fuse tree_top via last-block + __threadfence();
// per-block device-scope fences cost ~100 µs at 1024 blocks on MI355X.
// R11: 16-lane reductions are DPP butterflies (VALU-only). Bit-identical to
// shfl; gain −1.7 µs -> reductions were not the bottleneck.
// R12: attn wave = (leaf-pair p × 2 heads × 2 n); sibling leaf via lane^32
// shuffle; tree rows loaded once per pair. Gain −3.3 µs.
// R13 (this round): attn fully straight-lined. Inactive tree columns load
// the dummy slot (2046; L1-hot, same address for all waves) instead of
// branching around the gather -> all 13 global loads issue back-to-back
// (max MLP, one waitcnt cluster), and all per-column masking is v_cndmask
// (select, NOT multiply: dummy data is harness poison and may be NaN).
#define WSSLOTS 2048
#define ROWF4   (DIM / 4)              // 16 granules per row
#define HSTRIDE (HEADS * ROWF4)        // granule stride between rows (n or slot)
#define KVBYTES ((size_t)BATCH * WSSLOTS * HEADS * 256)   // combined ws bytes

__device__ __forceinline__ int level_offset(int j) {
    return (j == 0) ? 0 : (2 * NSEQ - ((2 * NSEQ) >> j));
}

__device__ __forceinline__ float dot4(float4 a, float4 b) {
    return a.x * b.x + a.y * b.y + a.z * b.z + a.w * b.w;
}

// ---- DPP 16-lane butterfly sum (no DS ops; fuses to v_add_f32_dpp).
// {xor1, xor2, mirror7, mirror15} form a GF(2) basis of the 16-lane space.
template <int CTRL>
__device__ __forceinline__ float dpp_radd(float x) {
    int y = __builtin_amdgcn_update_dpp(0, __float_as_int(x), CTRL, 0xF, 0xF, true);
    return x + __int_as_float(y);
}
__device__ __forceinline__ float rsum16(float x) {
    x = dpp_radd<0xB1>(x);
    x = dpp_radd<0x4E>(x);
    x = dpp_radd<0x141>(x);
    x = dpp_radd<0x140>(x);
    return x;
}

// ---- bf16 pack/unpack (RNE) ----
__device__ __forceinline__ unsigned short bf16rne(float x) {
    unsigned u = __float_as_uint(x);
    return (unsigned short)((u + 0x7FFFu + ((u >> 16) & 1u)) >> 16);
}
__device__ __forceinline__ unsigned pack2(float a, float b) {
    return (unsigned)bf16rne(a) | ((unsigned)bf16rne(b) << 16);
}
__device__ __forceinline__ uint4 packKV(float4 k, float4 v) {
    return make_uint4(pack2(k.x, k.y), pack2(k.z, k.w),
                      pack2(v.x, v.y), pack2(v.z, v.w));
}
__device__ __forceinline__ float2 unpack2(unsigned u) {
    return make_float2(__uint_as_float(u << 16),
                       __uint_as_float(u & 0xFFFF0000u));
}
__device__ __forceinline__ float4 unpackK(uint4 p) {
    float2 a = unpack2(p.x), b = unpack2(p.y);
    return make_float4(a.x, a.y, b.x, b.y);
}
__device__ __forceinline__ float4 unpackV(uint4 p) {
    float2 a = unpack2(p.z), b = unpack2(p.w);
    return make_float4(a.x, a.y, b.x, b.y);
}

__device__ __forceinline__ void reduce3_16(float& a, float& b, float& c) {
    a = rsum16(a);
    b = rsum16(b);
    c = rsum16(c);
}

__device__ __forceinline__ void reduce6_16(float& a, float& b, float& c,
                                           float& d, float& e, float& f) {
    a = rsum16(a);
    b = rsum16(b);
    c = rsum16(c);
    d = rsum16(d);
    e = rsum16(e);
    f = rsum16(f);
}

// Parent = 3-way softmax mix of {mean, child0, child1}; 16 lanes / parent.
__device__ __forceinline__ void make_parent4(float4 k0, float4 k1, float4 v0, float4 v1,
                                             float4& kc, float4& vc) {
    float4 kp, vp;
    kp.x = 0.5f * (k0.x + k1.x); kp.y = 0.5f * (k0.y + k1.y);
    kp.z = 0.5f * (k0.z + k1.z); kp.w = 0.5f * (k0.w + k1.w);
    vp.x = 0.5f * (v0.x + v1.x); vp.y = 0.5f * (v0.y + v1.y);
    vp.z = 0.5f * (v0.z + v1.z); vp.w = 0.5f * (v0.w + v1.w);
    float ss = dot4(kp, kp), sa = dot4(kp, k0), sb = dot4(kp, k1);
    reduce3_16(ss, sa, sb);
    ss *= SCALE; sa *= SCALE; sb *= SCALE;
    float mx = fmaxf(ss, fmaxf(sa, sb));
    float es = __expf(ss - mx), ea = __expf(sa - mx), eb = __expf(sb - mx);
    float inv = 1.0f / (es + ea + eb + 1e-9f);
    es *= inv; ea *= inv; eb *= inv;
    kc.x = es * kp.x + ea * k0.x + eb * k1.x;
    kc.y = es * kp.y + ea * k0.y + eb * k1.y;
    kc.z = es * kp.z + ea * k0.z + eb * k1.z;
    kc.w = es * kp.w + ea * k0.w + eb * k1.w;
    vc.x = es * vp.x + ea * v0.x + eb * v1.x;
    vc.y = es * vp.y + ea * v0.y + eb * v1.y;
    vc.z = es * vp.z + ea * v0.z + eb * v1.z;
    vc.w = es * vp.w + ea * v0.w + eb * v1.w;
}

// Two independent sibling mixes (ILP; DPP chains interleave in the VALU).
__device__ __forceinline__ void make_parent_pair4(const float4* k, const float4* v,
                                                  float4& ka, float4& va,
                                                  float4& kb, float4& vb) {
    float4 kpa, vpa, kpb, vpb;
    kpa.x = 0.5f * (k[0].x + k[1].x); kpa.y = 0.5f * (k[0].y + k[1].y);
    kpa.z = 0.5f * (k[0].z + k[1].z); kpa.w = 0.5f * (k[0].w + k[1].w);
    vpa.x = 0.5f * (v[0].x + v[1].x); vpa.y = 0.5f * (v[0].y + v[1].y);
    vpa.z = 0.5f * (v[0].z + v[1].z); vpa.w = 0.5f * (v[0].w + v[1].w);
    kpb.x = 0.5f * (k[2].x + k[3].x); kpb.y = 0.5f * (k[2].y + k[3].y);
    kpb.z = 0.5f * (k[2].z + k[3].z); kpb.w = 0.5f * (k[2].w + k[3].w);
    vpb.x = 0.5f * (v[2].x + v[3].x); vpb.y = 0.5f * (v[2].y + v[3].y);
    vpb.z = 0.5f * (v[2].z + v[3].z); vpb.w = 0.5f * (v[2].w + v[3].w);
    float ssa = dot4(kpa, kpa), saa = dot4(kpa, k[0]), sba = dot4(kpa, k[1]);
    float ssb = dot4(kpb, kpb), sab = dot4(kpb, k[2]), sbb = dot4(kpb, k[3]);
    reduce6_16(ssa, saa, sba, ssb, sab, sbb);
    ssa *= SCALE; saa *= SCALE; sba *= SCALE;
    ssb *= SCALE; sab *= SCALE; sbb *= SCALE;
    float mxa = fmaxf(ssa, fmaxf(saa, sba));
    float mxb = fmaxf(ssb, fmaxf(sab, sbb));
    float esa = __expf(ssa - mxa), eaa = __expf(saa - mxa), eba = __expf(sba - mxa);
    float esb = __expf(ssb - mxb), eab = __expf(sab - mxb), ebb = __expf(sbb - mxb);
    float iva = 1.0f / (esa + eaa + eba + 1e-9f);
    float ivb = 1.0f / (esb + eab + ebb + 1e-9f);
    esa *= iva; eaa *= iva; eba *= iva;
    esb *= ivb; eab *= ivb; ebb *= ivb;
    ka.x = esa * kpa.x + eaa * k[0].x + eba * k[1].x;
    ka.y = esa * kpa.y + eaa * k[0].y + eba * k[1].y;
    ka.z = esa * kpa.z + eaa * k[0].z + eba * k[1].z;
    ka.w = esa * kpa.w + eaa * k[0].w + eba * k[1].w;
    va.x = esa * vpa.x + eaa * v[0].x + eba * v[1].x;
    va.y = esa * vpa.y + eaa * v[0].y + eba * v[1].y;
    va.z = esa * vpa.z + eaa * v[0].z + eba * v[1].z;
    va.w = esa * vpa.w + eaa * v[0].w + eba * v[1].w;
    kb.x = esb * kpb.x + eab * k[2].x + ebb * k[3].x;
    kb.y = esb * kpb.y + eab * k[2].y + ebb * k[3].y;
    kb.z = esb * kpb.z + eab * k[2].z + ebb * k[3].z;
    kb.w = esb * kpb.w + eab * k[2].w + ebb * k[3].w;
    vb.x = esb * vpb.x + eab * v[2].x + ebb * v[3].x;
    vb.y = esb * vpb.y + eab * v[2].y + ebb * v[3].y;
    vb.z = esb * vpb.z + eab * v[2].z + ebb * v[3].z;
    vb.w = esb * vpb.w + eab * v[2].w + ebb * v[3].w;
}

// 4-ary consolidation: 4 child rows -> 2 parents + 1 grandparent, each stored
// as ONE combined bf16 KV row (3 stores instead of 6).
__device__ __forceinline__ void quad_step(const float4* k, const float4* v,
                                          uint4* KVw,
                                          size_t pRow0, size_t gRow,   // granule offsets (+t)
                                          int t,
                                          float4& kg, float4& vg) {
    float4 ka, va, kb, vb;
    make_parent_pair4(k, v, ka, va, kb, vb);
    KVw[pRow0 + t] = packKV(ka, va);
    KVw[pRow0 + HSTRIDE + t] = packKV(kb, vb);
    make_parent4(ka, kb, va, vb, kg, vg);
    KVw[gRow + t] = packKV(kg, vg);
}

// ---- Kernel A: tree levels 1..6 for one 64-leaf chunk. 1024 blocks (b,h,c).
__global__ __launch_bounds__(256) void tree_low(const float* __restrict__ K,
                                                const float* __restrict__ V,
                                                uint4* __restrict__ KVw,
                                                float* __restrict__ Kw6,
                                                float* __restrict__ Vw6) {
    __shared__ float4 Kb[20 * ROWF4];   // rows [0,16): lvl2 ; rows [16,20): lvl4
    __shared__ float4 Vb[20 * ROWF4];
    const float4* K4 = (const float4*)K;
    const float4* V4 = (const float4*)V;
    float4* Kw6f = (float4*)Kw6;
    float4* Vw6f = (float4*)Vw6;

    int bid = blockIdx.x;
    int c = bid & 31;
    int h = (bid >> 5) & 15;
    int b = bid >> 9;
    int lane = threadIdx.x & 63;
    int gg = (threadIdx.x >> 6) * 4 + (lane >> 4);   // group 0..15
    int t = lane & 15;

    size_t wsBase = (size_t)(b * WSSLOTS) * HSTRIDE + h * ROWF4;  // + slot*HSTRIDE + t

    // Round A: 16 groups, 4 leaves each -> lvl1 pair + lvl2 node
    {
        int n0 = c * 64 + 4 * gg;
        const float4* Kr = K4 + ((size_t)((b * NSEQ + n0) * HEADS + h)) * ROWF4;
        const float4* Vr = V4 + ((size_t)((b * NSEQ + n0) * HEADS + h)) * ROWF4;
        float4 k[4], v[4];
#pragma unroll
        for (int j = 0; j < 4; ++j) { k[j] = Kr[j * HSTRIDE + t]; v[j] = Vr[j * HSTRIDE + t]; }
        int s1 = c * 32 + 2 * gg;          // lvl1 slots s1, s1+1
        int s2 = 1024 + c * 16 + gg;       // lvl2 slot
        float4 kg, vg;
        quad_step(k, v, KVw, wsBase + (size_t)s1 * HSTRIDE,
                  wsBase + (size_t)s2 * HSTRIDE, t, kg, vg);
        Kb[gg * ROWF4 + t] = kg;  Vb[gg * ROWF4 + t] = vg;
    }
    __syncthreads();
    // Round B: groups 0..3, lvl2 rows -> lvl3 pair + lvl4 node
    if (gg < 4) {
        float4 k[4], v[4];
#pragma unroll
        for (int j = 0; j < 4; ++j) {
            k[j] = Kb[(4 * gg + j) * ROWF4 + t];
            v[j] = Vb[(4 * gg + j) * ROWF4 + t];
        }
        int s3 = 1536 + c * 8 + 2 * gg;
        int s4 = 1792 + c * 4 + gg;
        float4 kg, vg;
        quad_step(k, v, KVw, wsBase + (size_t)s3 * HSTRIDE,
                  wsBase + (size_t)s4 * HSTRIDE, t, kg, vg);
        Kb[(16 + gg) * ROWF4 + t] = kg;  Vb[(16 + gg) * ROWF4 + t] = vg;
    }
    __syncthreads();
    // Round C: group 0, lvl4 rows -> lvl5 pair + lvl6 node (+ fp32 lvl6 stash)
    if (gg == 0) {
        float4 k[4], v[4];
#pragma unroll
        for (int j = 0; j < 4; ++j) {
            k[j] = Kb[(16 + j) * ROWF4 + t];
            v[j] = Vb[(16 + j) * ROWF4 + t];
        }
        int s5 = 1920 + c * 2;
        int s6 = 1984 + c;
        float4 kg, vg;
        quad_step(k, v, KVw, wsBase + (size_t)s5 * HSTRIDE,
                  wsBase + (size_t)s6 * HSTRIDE, t, kg, vg);
        size_t st = ((size_t)((b * 32 + c) * HEADS + h)) * ROWF4 + t;
        Kw6f[st] = kg;  Vw6f[st] = vg;     // fp32 stash for tree_top
    }
}

// ---- Kernel B: tree levels 7..10 for one (b,h). 32 blocks, 2 rounds, 1 barrier.
// Builds from the fp32 lvl6 stash (no bf16 re-rounding compounding).
__global__ __launch_bounds__(256) void tree_top(uint4* __restrict__ KVw,
                                                const float* __restrict__ Kw6,
                                                const float* __restrict__ Vw6) {
    __shared__ float4 Kb[8 * ROWF4];    // lvl8 nodes (fp32)
    __shared__ float4 Vb[8 * ROWF4];
    const float4* Kw6f = (const float4*)Kw6;
    const float4* Vw6f = (const float4*)Vw6;

    int h = blockIdx.x & 15, b = blockIdx.x >> 4;
    int lane = threadIdx.x & 63;
    int gg = (threadIdx.x >> 6) * 4 + (lane >> 4);
    int t = lane & 15;
    size_t wsBase = (size_t)(b * WSSLOTS) * HSTRIDE + h * ROWF4;

    // Round A: groups 0..7: 4 fp32 lvl6 rows -> lvl7 pair + lvl8 node
    if (gg < 8) {
        float4 k[4], v[4];
#pragma unroll
        for (int j = 0; j < 4; ++j) {
            size_t r = ((size_t)((b * 32 + 4 * gg + j) * HEADS + h)) * ROWF4 + t;
            k[j] = Kw6f[r]; v[j] = Vw6f[r];
        }
        int s7 = 2016 + 2 * gg;
        int s8 = 2032 + gg;
        float4 kg, vg;
        quad_step(k, v, KVw, wsBase + (size_t)s7 * HSTRIDE,
                  wsBase + (size_t)s8 * HSTRIDE, t, kg, vg);
        Kb[gg * ROWF4 + t] = kg;  Vb[gg * ROWF4 + t] = vg;
    }
    __syncthreads();
    // Round B: groups 0..1: 4 fp32 lvl8 rows -> lvl9 pair + lvl10 node
    if (gg < 2) {
        float4 k[4], v[4];
#pragma unroll
        for (int j = 0; j < 4; ++j) {
            k[j] = Kb[(4 * gg + j) * ROWF4 + t];
            v[j] = Vb[(4 * gg + j) * ROWF4 + t];
        }
        int s9  = 2040 + 2 * gg;
        int s10 = 2044 + gg;
        float4 kg, vg;
        quad_step(k, v, KVw, wsBase + (size_t)s9 * HSTRIDE,
                  wsBase + (size_t)s10 * HSTRIDE, t, kg, vg);
    }
}

// ---- Kernel C: attention. One wave = one leaf pair (n=2p, 2p+1) × 2 heads.
// Straight-line body (R13): inactive tree columns gather the dummy slot
// (2046 — unused, identical address for every wave -> L1-hot broadcast) so
// ALL loads issue unconditionally back-to-back; every per-column mask is a
// v_cndmask select (poison-safe: never multiply-mask, dummy data may be NaN).
__global__ __launch_bounds__(256) void attn(const float* __restrict__ Q,
                                            const float* __restrict__ K,
                                            const float* __restrict__ V,
                                            const uint4* __restrict__ KVw,
                                            float* __restrict__ out) {
    const float4* Q4 = (const float4*)Q;
    const float4* K4 = (const float4*)K;
    const float4* V4 = (const float4*)V;
    float4* O4 = (float4*)out;

    int bid = blockIdx.x;                              // 0..4095
    int vbid = ((bid & 7) << 9) | (bid >> 3);          // bijective XCD remap
    int w = vbid * 4 + (threadIdx.x >> 6);             // wave id over B*(N/2)*(H/2)
    int lane = threadIdx.x & 63;
    int g2 = lane >> 5;                                // which n of the pair
    int hh = (lane >> 4) & 1;                          // which head of the pair
    int t = lane & 15;
    int hp = w & 7;                                    // head pair 0..7
    int p  = (w >> 3) & 1023;                          // leaf pair
    int b  = w >> 13;
    int n  = 2 * p + g2;
    int h  = 2 * hp + hh;

    int row0 = (b * NSEQ + n) * HSTRIDE;               // self leaf / Q / out
    int hoff = h * ROWF4 + t;

    // tree column l (2..11) active iff bit (l-2) of p set (wave-uniform).
    unsigned active = 1u | (((unsigned)p & 0x3FFu) << 2);
    active = (unsigned)__builtin_amdgcn_readfirstlane((int)active);

    int rowt[10];
#pragma unroll
    for (int l = 2; l < 12; ++l) {
        int j = l - 1;
        int slot = level_offset(j) - NSEQ + ((n >> j) ^ 1);   // uniform (j>=1)
        slot = (active & (1u << l)) ? slot : 2046;            // dummy redirect
        rowt[l - 2] = (b * WSSLOTS + slot) * HSTRIDE;
    }

    // All loads unconditional, back-to-back (max loads-in-flight).
    float4 q4 = Q4[row0 + hoff];
    float4 k0 = K4[row0 + hoff];       // self leaf (serves as sibling for the
    float4 v0 = V4[row0 + hoff];       // other half via lane^32 exchange)
    uint4 kv[10];
#pragma unroll
    for (int l = 2; l < 12; ++l)
        kv[l - 2] = KVw[rowt[l - 2] + hoff];

    q4.x *= SCALE; q4.y *= SCALE; q4.z *= SCALE; q4.w *= SCALE;

    // sibling leaf fragments from the other 32-lane half (no extra loads)
    float4 ks, vs;
    ks.x = __shfl_xor(k0.x, 32, 64); ks.y = __shfl_xor(k0.y, 32, 64);
    ks.z = __shfl_xor(k0.z, 32, 64); ks.w = __shfl_xor(k0.w, 32, 64);
    vs.x = __shfl_xor(v0.x, 32, 64); vs.y = __shfl_xor(v0.y, 32, 64);
    vs.z = __shfl_xor(v0.z, 32, 64); vs.w = __shfl_xor(v0.w, 32, 64);

    float s[12];
    s[0] = dot4(q4, k0);
    s[1] = dot4(q4, ks);               // only used by odd-n half
#pragma unroll
    for (int l = 2; l < 12; ++l)
        s[l] = dot4(q4, unpackK(kv[l - 2]));

    s[0] = rsum16(s[0]);
    s[1] = rsum16(s[1]);
#pragma unroll
    for (int l = 2; l < 12; ++l)
        s[l] = rsum16(s[l]);

    const float NEG = -3.402823466e+38f;
    float mx = s[0];
    mx = fmaxf(mx, g2 ? s[1] : NEG);                   // col1 masked for even n
#pragma unroll
    for (int l = 2; l < 12; ++l)
        mx = fmaxf(mx, (active & (1u << l)) ? s[l] : NEG);

    float sum;
    {
        float e0 = __expf(s[0] - mx);
        float e1 = __expf(s[1] - mx);
        e1 = g2 ? e1 : 0.f;                            // select, poison-safe
        s[0] = e0; s[1] = e1;
        sum = e0 + e1;
    }
#pragma unroll
    for (int l = 2; l < 12; ++l) {
        float e = __expf(s[l] - mx);
        e = (active & (1u << l)) ? e : 0.f;            // select, poison-safe
        s[l] = e;
        sum += e;
    }
    float inv = 1.0f / sum;

    float4 o;
    o.x = s[0] * v0.x + s[1] * vs.x;
    o.y = s[0] * v0.y + s[1] * vs.y;
    o.z = s[0] * v0.z + s[1] * vs.z;
    o.w = s[0] * v0.w + s[1] * vs.w;
#pragma unroll
    for (int l = 2; l < 12; ++l) {
        float4 vv = unpackV(kv[l - 2]);                // s[l]==0 kills poison
        float wl = s[l];
        o.x += wl * vv.x; o.y += wl * vv.y;
        o.z += wl * vv.z; o.w += wl * vv.w;
    }
    O4[row0 + hoff] = make_float4(o.x * inv, o.y * inv, o.z * inv, o.w * inv);
}

extern "C" void kernel_launch(void* const* d_in, const int* in_sizes, int n_in,
                              void* d_out, int out_size, void* d_ws, size_t ws_size,
                              hipStream_t stream) {
    const float* Q = (const float*)d_in[0];
    const float* K = (const float*)d_in[1];
    const float* V = (const float*)d_in[2];
    float* out = (float*)d_out;
    uint4* KVw = (uint4*)d_ws;                         // combined bf16 KV, 16.78 MB
    float* Kw6 = (float*)((char*)d_ws + KVBYTES);      // fp32 lvl6 stash, 262 KB
    float* Vw6 = Kw6 + (size_t)BATCH * 32 * HEADS * DIM;

    tree_low<<<1024, 256, 0, stream>>>(K, V, KVw, Kw6, Vw6);
    tree_top<<<BATCH * HEADS, 256, 0, stream>>>(KVw, Kw6, Vw6);
    attn<<<(BATCH * (NSEQ / 2) * (HEADS / 2)) / 4, 256, 0, stream>>>(Q, K, V, KVw, out);
}

// Round 4
// 108.155 us; speedup vs baseline: 1.0361x; 1.0361x over previous
//
#include <hip/hip_runtime.h>

#define NSEQ   2048
#define HEADS  16
#define DIM    64
#define BATCH  2
#define SCALE  0.125f      // 1/sqrt(64)

// Workspace layout:
//   KVw : bf16 combined rows [b][slot][h][granule t]  where granule t (16 B)
//         = {k[4t..4t+3], v[4t..4t+3]} both bf16x4.  16.78 MB total.
//         One dwordx4 per (slot,h,t) fetches BOTH K and V fragments.
//   Kw6/Vw6 : fp32 lvl6 stash [b][32][h][d], 262 KB each (tree_top builds
//         from fp32 so bf16 rounding never compounds).
// Slot map: lvl1 0..1023 (DEAD since R14 — never written/read), lvl2 1024..,
// lvl3 1536.., lvl4 1792.., lvl5 1920.., lvl6 1984.., lvl7 2016..,
// lvl8 2032.., lvl9 2040.., lvl10 2044,2045.
// Invariant: parent(level_offset(j)+i) = level_offset(j+1)+i/2.
// NOTE (R8 lesson): do NOT fuse tree_top via last-block + __threadfence();
// per-block device-scope fences cost ~100 µs at 1024 blocks on MI355X.
// R11: 16-lane reductions are DPP butterflies (VALU-only). −1.7 µs.
// R12: attn wave = (leaf-pair p × 2 heads × 2 n); sibling leaf via lane^32
// shuffle; tree rows loaded once per pair. −3.3 µs.
// R13: straight-line + dummy-slot gathers: +2.1 µs -> REVERTED to R12 form.
// R14 (this round): lvl1 never touches the workspace. attn blocks hold pairs
// {4Q..4Q+3} of ONE head-pair; each wave computes its own lvl1 parent in
// fp32 from leaf registers (reference-exact arithmetic), publishes K,V rows
// via LDS, and consumes the partner wave's (p^1) node for column 2.
// tree_low Round A stores only lvl2. Saves 8.4 MB writes + 8.4 MB reads +
// one scattered gather per attn wave; col2 precision improves (fp32).
#define WSSLOTS 2048
#define ROWF4   (DIM / 4)              // 16 granules per row
#define HSTRIDE (HEADS * ROWF4)        // granule stride between rows (n or slot)
#define KVBYTES ((size_t)BATCH * WSSLOTS * HEADS * 256)   // combined ws bytes

__device__ __forceinline__ int level_offset(int j) {
    return (j == 0) ? 0 : (2 * NSEQ - ((2 * NSEQ) >> j));
}

__device__ __forceinline__ float dot4(float4 a, float4 b) {
    return a.x * b.x + a.y * b.y + a.z * b.z + a.w * b.w;
}

// ---- DPP 16-lane butterfly sum (no DS ops; fuses to v_add_f32_dpp).
// {xor1, xor2, mirror7, mirror15} form a GF(2) basis of the 16-lane space.
template <int CTRL>
__device__ __forceinline__ float dpp_radd(float x) {
    int y = __builtin_amdgcn_update_dpp(0, __float_as_int(x), CTRL, 0xF, 0xF, true);
    return x + __int_as_float(y);
}
__device__ __forceinline__ float rsum16(float x) {
    x = dpp_radd<0xB1>(x);
    x = dpp_radd<0x4E>(x);
    x = dpp_radd<0x141>(x);
    x = dpp_radd<0x140>(x);
    return x;
}

// ---- bf16 pack/unpack (RNE) ----
__device__ __forceinline__ unsigned short bf16rne(float x) {
    unsigned u = __float_as_uint(x);
    return (unsigned short)((u + 0x7FFFu + ((u >> 16) & 1u)) >> 16);
}
__device__ __forceinline__ unsigned pack2(float a, float b) {
    return (unsigned)bf16rne(a) | ((unsigned)bf16rne(b) << 16);
}
__device__ __forceinline__ uint4 packKV(float4 k, float4 v) {
    return make_uint4(pack2(k.x, k.y), pack2(k.z, k.w),
                      pack2(v.x, v.y), pack2(v.z, v.w));
}
__device__ __forceinline__ float2 unpack2(unsigned u) {
    return make_float2(__uint_as_float(u << 16),
                       __uint_as_float(u & 0xFFFF0000u));
}
__device__ __forceinline__ float4 unpackK(uint4 p) {
    float2 a = unpack2(p.x), b = unpack2(p.y);
    return make_float4(a.x, a.y, b.x, b.y);
}
__device__ __forceinline__ float4 unpackV(uint4 p) {
    float2 a = unpack2(p.z), b = unpack2(p.w);
    return make_float4(a.x, a.y, b.x, b.y);
}

__device__ __forceinline__ void reduce3_16(float& a, float& b, float& c) {
    a = rsum16(a);
    b = rsum16(b);
    c = rsum16(c);
}

__device__ __forceinline__ void reduce6_16(float& a, float& b, float& c,
                                           float& d, float& e, float& f) {
    a = rsum16(a);
    b = rsum16(b);
    c = rsum16(c);
    d = rsum16(d);
    e = rsum16(e);
    f = rsum16(f);
}

// Parent = 3-way softmax mix of {mean, child0, child1}; 16 lanes / parent.
// NOTE: symmetric under child swap up to fp addition order in the denom
// (±1 ulp) — both attn wave-halves compute the same parent independently.
__device__ __forceinline__ void make_parent4(float4 k0, float4 k1, float4 v0, float4 v1,
                                             float4& kc, float4& vc) {
    float4 kp, vp;
    kp.x = 0.5f * (k0.x + k1.x); kp.y = 0.5f * (k0.y + k1.y);
    kp.z = 0.5f * (k0.z + k1.z); kp.w = 0.5f * (k0.w + k1.w);
    vp.x = 0.5f * (v0.x + v1.x); vp.y = 0.5f * (v0.y + v1.y);
    vp.z = 0.5f * (v0.z + v1.z); vp.w = 0.5f * (v0.w + v1.w);
    float ss = dot4(kp, kp), sa = dot4(kp, k0), sb = dot4(kp, k1);
    reduce3_16(ss, sa, sb);
    ss *= SCALE; sa *= SCALE; sb *= SCALE;
    float mx = fmaxf(ss, fmaxf(sa, sb));
    float es = __expf(ss - mx), ea = __expf(sa - mx), eb = __expf(sb - mx);
    float inv = 1.0f / (es + ea + eb + 1e-9f);
    es *= inv; ea *= inv; eb *= inv;
    kc.x = es * kp.x + ea * k0.x + eb * k1.x;
    kc.y = es * kp.y + ea * k0.y + eb * k1.y;
    kc.z = es * kp.z + ea * k0.z + eb * k1.z;
    kc.w = es * kp.w + ea * k0.w + eb * k1.w;
    vc.x = es * vp.x + ea * v0.x + eb * v1.x;
    vc.y = es * vp.y + ea * v0.y + eb * v1.y;
    vc.z = es * vp.z + ea * v0.z + eb * v1.z;
    vc.w = es * vp.w + ea * v0.w + eb * v1.w;
}

// Two independent sibling mixes (ILP; DPP chains interleave in the VALU).
__device__ __forceinline__ void make_parent_pair4(const float4* k, const float4* v,
                                                  float4& ka, float4& va,
                                                  float4& kb, float4& vb) {
    float4 kpa, vpa, kpb, vpb;
    kpa.x = 0.5f * (k[0].x + k[1].x); kpa.y = 0.5f * (k[0].y + k[1].y);
    kpa.z = 0.5f * (k[0].z + k[1].z); kpa.w = 0.5f * (k[0].w + k[1].w);
    vpa.x = 0.5f * (v[0].x + v[1].x); vpa.y = 0.5f * (v[0].y + v[1].y);
    vpa.z = 0.5f * (v[0].z + v[1].z); vpa.w = 0.5f * (v[0].w + v[1].w);
    kpb.x = 0.5f * (k[2].x + k[3].x); kpb.y = 0.5f * (k[2].y + k[3].y);
    kpb.z = 0.5f * (k[2].z + k[3].z); kpb.w = 0.5f * (k[2].w + k[3].w);
    vpb.x = 0.5f * (v[2].x + v[3].x); vpb.y = 0.5f * (v[2].y + v[3].y);
    vpb.z = 0.5f * (v[2].z + v[3].z); vpb.w = 0.5f * (v[2].w + v[3].w);
    float ssa = dot4(kpa, kpa), saa = dot4(kpa, k[0]), sba = dot4(kpa, k[1]);
    float ssb = dot4(kpb, kpb), sab = dot4(kpb, k[2]), sbb = dot4(kpb, k[3]);
    reduce6_16(ssa, saa, sba, ssb, sab, sbb);
    ssa *= SCALE; saa *= SCALE; sba *= SCALE;
    ssb *= SCALE; sab *= SCALE; sbb *= SCALE;
    float mxa = fmaxf(ssa, fmaxf(saa, sba));
    float mxb = fmaxf(ssb, fmaxf(sab, sbb));
    float esa = __expf(ssa - mxa), eaa = __expf(saa - mxa), eba = __expf(sba - mxa);
    float esb = __expf(ssb - mxb), eab = __expf(sab - mxb), ebb = __expf(sbb - mxb);
    float iva = 1.0f / (esa + eaa + eba + 1e-9f);
    float ivb = 1.0f / (esb + eab + ebb + 1e-9f);
    esa *= iva; eaa *= iva; eba *= iva;
    esb *= ivb; eab *= ivb; ebb *= ivb;
    ka.x = esa * kpa.x + eaa * k[0].x + eba * k[1].x;
    ka.y = esa * kpa.y + eaa * k[0].y + eba * k[1].y;
    ka.z = esa * kpa.z + eaa * k[0].z + eba * k[1].z;
    ka.w = esa * kpa.w + eaa * k[0].w + eba * k[1].w;
    va.x = esa * vpa.x + eaa * v[0].x + eba * v[1].x;
    va.y = esa * vpa.y + eaa * v[0].y + eba * v[1].y;
    va.z = esa * vpa.z + eaa * v[0].z + eba * v[1].z;
    va.w = esa * vpa.w + eaa * v[0].w + eba * v[1].w;
    kb.x = esb * kpb.x + eab * k[2].x + ebb * k[3].x;
    kb.y = esb * kpb.y + eab * k[2].y + ebb * k[3].y;
    kb.z = esb * kpb.z + eab * k[2].z + ebb * k[3].z;
    kb.w = esb * kpb.w + eab * k[2].w + ebb * k[3].w;
    vb.x = esb * vpb.x + eab * v[2].x + ebb * v[3].x;
    vb.y = esb * vpb.y + eab * v[2].y + ebb * v[3].y;
    vb.z = esb * vpb.z + eab * v[2].z + ebb * v[3].z;
    vb.w = esb * vpb.w + eab * v[2].w + ebb * v[3].w;
}

// 4-ary consolidation: 4 child rows -> 2 parents + 1 grandparent, each stored
// as ONE combined bf16 KV row (3 stores instead of 6).
__device__ __forceinline__ void quad_step(const float4* k, const float4* v,
                                          uint4* KVw,
                                          size_t pRow0, size_t gRow,   // granule offsets (+t)
                                          int t,
                                          float4& kg, float4& vg) {
    float4 ka, va, kb, vb;
    make_parent_pair4(k, v, ka, va, kb, vb);
    KVw[pRow0 + t] = packKV(ka, va);
    KVw[pRow0 + HSTRIDE + t] = packKV(kb, vb);
    make_parent4(ka, kb, va, vb, kg, vg);
    KVw[gRow + t] = packKV(kg, vg);
}

// R14 variant: store only the grandparent (Round A: lvl1 no longer
// materialized in the workspace — attn rebuilds it in-register).
__device__ __forceinline__ void quad_step_g(const float4* k, const float4* v,
                                            uint4* KVw, size_t gRow, int t,
                                            float4& kg, float4& vg) {
    float4 ka, va, kb, vb;
    make_parent_pair4(k, v, ka, va, kb, vb);
    make_parent4(ka, kb, va, vb, kg, vg);
    KVw[gRow + t] = packKV(kg, vg);
}

// ---- Kernel A: tree levels 1..6 for one 64-leaf chunk. 1024 blocks (b,h,c).
__global__ __launch_bounds__(256) void tree_low(const float* __restrict__ K,
                                                const float* __restrict__ V,
                                                uint4* __restrict__ KVw,
                                                float* __restrict__ Kw6,
                                                float* __restrict__ Vw6) {
    __shared__ float4 Kb[20 * ROWF4];   // rows [0,16): lvl2 ; rows [16,20): lvl4
    __shared__ float4 Vb[20 * ROWF4];
    const float4* K4 = (const float4*)K;
    const float4* V4 = (const float4*)V;
    float4* Kw6f = (float4*)Kw6;
    float4* Vw6f = (float4*)Vw6;

    int bid = blockIdx.x;
    int c = bid & 31;
    int h = (bid >> 5) & 15;
    int b = bid >> 9;
    int lane = threadIdx.x & 63;
    int gg = (threadIdx.x >> 6) * 4 + (lane >> 4);   // group 0..15
    int t = lane & 15;

    size_t wsBase = (size_t)(b * WSSLOTS) * HSTRIDE + h * ROWF4;  // + slot*HSTRIDE + t

    // Round A: 16 groups, 4 leaves each -> lvl2 node only (lvl1 dropped, R14)
    {
        int n0 = c * 64 + 4 * gg;
        const float4* Kr = K4 + ((size_t)((b * NSEQ + n0) * HEADS + h)) * ROWF4;
        const float4* Vr = V4 + ((size_t)((b * NSEQ + n0) * HEADS + h)) * ROWF4;
        float4 k[4], v[4];
#pragma unroll
        for (int j = 0; j < 4; ++j) { k[j] = Kr[j * HSTRIDE + t]; v[j] = Vr[j * HSTRIDE + t]; }
        int s2 = 1024 + c * 16 + gg;       // lvl2 slot
        float4 kg, vg;
        quad_step_g(k, v, KVw, wsBase + (size_t)s2 * HSTRIDE, t, kg, vg);
        Kb[gg * ROWF4 + t] = kg;  Vb[gg * ROWF4 + t] = vg;
    }
    __syncthreads();
    // Round B: groups 0..3, lvl2 rows -> lvl3 pair + lvl4 node
    if (gg < 4) {
        float4 k[4], v[4];
#pragma unroll
        for (int j = 0; j < 4; ++j) {
            k[j] = Kb[(4 * gg + j) * ROWF4 + t];
            v[j] = Vb[(4 * gg + j) * ROWF4 + t];
        }
        int s3 = 1536 + c * 8 + 2 * gg;
        int s4 = 1792 + c * 4 + gg;
        float4 kg, vg;
        quad_step(k, v, KVw, wsBase + (size_t)s3 * HSTRIDE,
                  wsBase + (size_t)s4 * HSTRIDE, t, kg, vg);
        Kb[(16 + gg) * ROWF4 + t] = kg;  Vb[(16 + gg) * ROWF4 + t] = vg;
    }
    __syncthreads();
    // Round C: group 0, lvl4 rows -> lvl5 pair + lvl6 node (+ fp32 lvl6 stash)
    if (gg == 0) {
        float4 k[4], v[4];
#pragma unroll
        for (int j = 0; j < 4; ++j) {
            k[j] = Kb[(16 + j) * ROWF4 + t];
            v[j] = Vb[(16 + j) * ROWF4 + t];
        }
        int s5 = 1920 + c * 2;
        int s6 = 1984 + c;
        float4 kg, vg;
        quad_step(k, v, KVw, wsBase + (size_t)s5 * HSTRIDE,
                  wsBase + (size_t)s6 * HSTRIDE, t, kg, vg);
        size_t st = ((size_t)((b * 32 + c) * HEADS + h)) * ROWF4 + t;
        Kw6f[st] = kg;  Vw6f[st] = vg;     // fp32 stash for tree_top
    }
}

// ---- Kernel B: tree levels 7..10 for one (b,h). 32 blocks, 2 rounds, 1 barrier.
// Builds from the fp32 lvl6 stash (no bf16 re-rounding compounding).
__global__ __launch_bounds__(256) void tree_top(uint4* __restrict__ KVw,
                                                const float* __restrict__ Kw6,
                                                const float* __restrict__ Vw6) {
    __shared__ float4 Kb[8 * ROWF4];    // lvl8 nodes (fp32)
    __shared__ float4 Vb[8 * ROWF4];
    const float4* Kw6f = (const float4*)Kw6;
    const float4* Vw6f = (const float4*)Vw6;

    int h = blockIdx.x & 15, b = blockIdx.x >> 4;
    int lane = threadIdx.x & 63;
    int gg = (threadIdx.x >> 6) * 4 + (lane >> 4);
    int t = lane & 15;
    size_t wsBase = (size_t)(b * WSSLOTS) * HSTRIDE + h * ROWF4;

    // Round A: groups 0..7: 4 fp32 lvl6 rows -> lvl7 pair + lvl8 node
    if (gg < 8) {
        float4 k[4], v[4];
#pragma unroll
        for (int j = 0; j < 4; ++j) {
            size_t r = ((size_t)((b * 32 + 4 * gg + j) * HEADS + h)) * ROWF4 + t;
            k[j] = Kw6f[r]; v[j] = Vw6f[r];
        }
        int s7 = 2016 + 2 * gg;
        int s8 = 2032 + gg;
        float4 kg, vg;
        quad_step(k, v, KVw, wsBase + (size_t)s7 * HSTRIDE,
                  wsBase + (size_t)s8 * HSTRIDE, t, kg, vg);
        Kb[gg * ROWF4 + t] = kg;  Vb[gg * ROWF4 + t] = vg;
    }
    __syncthreads();
    // Round B: groups 0..1: 4 fp32 lvl8 rows -> lvl9 pair + lvl10 node
    if (gg < 2) {
        float4 k[4], v[4];
#pragma unroll
        for (int j = 0; j < 4; ++j) {
            k[j] = Kb[(4 * gg + j) * ROWF4 + t];
            v[j] = Vb[(4 * gg + j) * ROWF4 + t];
        }
        int s9  = 2040 + 2 * gg;
        int s10 = 2044 + gg;
        float4 kg, vg;
        quad_step(k, v, KVw, wsBase + (size_t)s9 * HSTRIDE,
                  wsBase + (size_t)s10 * HSTRIDE, t, kg, vg);
    }
}

// ---- Kernel C: attention. Block = (b, quad Q, head-pair hp); wave wid owns
// leaf pair p = 4Q+wid (2 n × 2 heads × 16 granules per wave).
// Column 2 (lvl1 node p^1): wave wid^1 computes it in fp32 from its leaf
// registers (reference-exact make_parent) and shares via LDS. No lvl1 in
// the workspace at all. Tree columns l=3..11 gathered from KVw (branchy,
// wave-uniform — R12 form; the R13 straight-line variant regressed).
__global__ __launch_bounds__(256) void attn(const float* __restrict__ Q,
                                            const float* __restrict__ K,
                                            const float* __restrict__ V,
                                            const uint4* __restrict__ KVw,
                                            float* __restrict__ out) {
    __shared__ float4 PK[4][2][16];    // [wid][hh][t] lvl1 parent K row (fp32)
    __shared__ float4 PV[4][2][16];    // [wid][hh][t] lvl1 parent V row (fp32)
    const float4* Q4 = (const float4*)Q;
    const float4* K4 = (const float4*)K;
    const float4* V4 = (const float4*)V;
    float4* O4 = (float4*)out;

    int bid = blockIdx.x;                              // 0..4095
    int vbid = ((bid & 7) << 9) | (bid >> 3);          // bijective XCD remap
    int wid = threadIdx.x >> 6;                        // wave in block: pair low bits
    int lane = threadIdx.x & 63;
    int g2 = lane >> 5;                                // which n of the pair
    int hh = (lane >> 4) & 1;                          // which head of the pair
    int t = lane & 15;
    int Qd = vbid & 255;                               // quad of pairs
    int hp = (vbid >> 8) & 7;                          // head pair
    int b  = vbid >> 11;
    int p  = 4 * Qd + wid;                             // leaf pair
    int n  = 2 * p + g2;
    int h  = 2 * hp + hh;

    int row0 = (b * NSEQ + n) * HSTRIDE;               // self leaf / Q / out
    int hoff = h * ROWF4 + t;

    // column l active iff bit (l-1) of n set; for l>=2 that is bit (l-2) of p
    // (wave-uniform).
    unsigned active = 1u | (((unsigned)p & 0x3FFu) << 2);
    active = (unsigned)__builtin_amdgcn_readfirstlane((int)active);

    int rowt[9];
#pragma unroll
    for (int l = 3; l < 12; ++l) {
        int j = l - 1;
        int slot = level_offset(j) - NSEQ + ((n >> j) ^ 1);   // uniform (j>=2)
        rowt[l - 3] = (b * WSSLOTS + slot) * HSTRIDE;
    }

    float4 q4 = Q4[row0 + hoff];
    float4 k0 = K4[row0 + hoff];       // self leaf
    float4 v0 = V4[row0 + hoff];
    uint4 kv[9];
#pragma unroll
    for (int l = 3; l < 12; ++l)
        if (active & (1u << l)) kv[l - 3] = KVw[rowt[l - 3] + hoff];

    // sibling leaf fragments from the other 32-lane half (no extra loads)
    float4 ks, vs;
    ks.x = __shfl_xor(k0.x, 32, 64); ks.y = __shfl_xor(k0.y, 32, 64);
    ks.z = __shfl_xor(k0.z, 32, 64); ks.w = __shfl_xor(k0.w, 32, 64);
    vs.x = __shfl_xor(v0.x, 32, 64); vs.y = __shfl_xor(v0.y, 32, 64);
    vs.z = __shfl_xor(v0.z, 32, 64); vs.w = __shfl_xor(v0.w, 32, 64);

    // Own pair's lvl1 parent, fp32, reference-exact (both halves compute the
    // same values; child order differs but the mix is symmetric).
    float4 kp1, vp1;
    make_parent4(k0, ks, v0, vs, kp1, vp1);
    if (lane < 32) { PK[wid][hh][t] = kp1; PV[wid][hh][t] = vp1; }
    __syncthreads();
    float4 kc2 = PK[wid ^ 1][hh][t];   // partner pair's lvl1 node (col 2)
    float4 vc2 = PV[wid ^ 1][hh][t];

    q4.x *= SCALE; q4.y *= SCALE; q4.z *= SCALE; q4.w *= SCALE;

    float s[12];
    s[0] = dot4(q4, k0);
    s[1] = dot4(q4, ks);               // only used by odd-n half
    s[2] = (active & 4u) ? dot4(q4, kc2) : 0.f;
#pragma unroll
    for (int l = 3; l < 12; ++l)
        s[l] = (active & (1u << l)) ? dot4(q4, unpackK(kv[l - 3])) : 0.f;

    s[0] = rsum16(s[0]);
    s[1] = rsum16(s[1]);
    if (active & 4u) s[2] = rsum16(s[2]);
#pragma unroll
    for (int l = 3; l < 12; ++l)
        if (active & (1u << l)) s[l] = rsum16(s[l]);

    const float NEG = -3.402823466e+38f;
    float mx = s[0];
    mx = fmaxf(mx, g2 ? s[1] : NEG);                   // col1 masked for even n
#pragma unroll
    for (int l = 2; l < 12; ++l)
        if (active & (1u << l)) mx = fmaxf(mx, s[l]);

    float sum;
    {
        float e0 = __expf(s[0] - mx);
        float e1 = __expf(s[1] - mx);
        e1 = g2 ? e1 : 0.f;
        s[0] = e0; s[1] = e1;
        sum = e0 + e1;
    }
#pragma unroll
    for (int l = 2; l < 12; ++l) {
        float e = (active & (1u << l)) ? __expf(s[l] - mx) : 0.f;
        s[l] = e;
        sum += e;
    }
    float inv = 1.0f / sum;

    float4 o;
    o.x = s[0] * v0.x + s[1] * vs.x + s[2] * vc2.x;    // s[2]==0 if inactive;
    o.y = s[0] * v0.y + s[1] * vs.y + s[2] * vc2.y;    // vc2 is real data (no
    o.z = s[0] * v0.z + s[1] * vs.z + s[2] * vc2.z;    // poison), so multiply-
    o.w = s[0] * v0.w + s[1] * vs.w + s[2] * vc2.w;    // mask is safe here.
#pragma unroll
    for (int l = 3; l < 12; ++l) {
        if (active & (1u << l)) {
            float4 vv = unpackV(kv[l - 3]);
            o.x += s[l] * vv.x; o.y += s[l] * vv.y;
            o.z += s[l] * vv.z; o.w += s[l] * vv.w;
        }
    }
    O4[row0 + hoff] = make_float4(o.x * inv, o.y * inv, o.z * inv, o.w * inv);
}

extern "C" void kernel_launch(void* const* d_in, const int* in_sizes, int n_in,
                              void* d_out, int out_size, void* d_ws, size_t ws_size,
                              hipStream_t stream) {
    const float* Q = (const float*)d_in[0];
    const float* K = (const float*)d_in[1];
    const float* V = (const float*)d_in[2];
    float* out = (float*)d_out;
    uint4* KVw = (uint4*)d_ws;                         // combined bf16 KV, 16.78 MB
    float* Kw6 = (float*)((char*)d_ws + KVBYTES);      // fp32 lvl6 stash, 262 KB
    float* Vw6 = Kw6 + (size_t)BATCH * 32 * HEADS * DIM;

    tree_low<<<1024, 256, 0, stream>>>(K, V, KVw, Kw6, Vw6);
    tree_top<<<BATCH * HEADS, 256, 0, stream>>>(KVw, Kw6, Vw6);
    attn<<<(BATCH * (NSEQ / 2) * (HEADS / 2)) / 4, 256, 0, stream>>>(Q, K, V, KVw, out);
}